// Round 2
// baseline (1227.091 us; speedup 1.0000x reference)
//
#include <hip/hip_runtime.h>

#define IN_DIM   512
#define OUT_DIM  256
#define N_MID    1280
#define N_NODES  1792
#define BATCH    16384
#define ROWS     16     // batch rows per workgroup
#define NT       256    // threads per workgroup
#define XPAD     520    // LDS row stride for x tile
#define KMAX     20     // max columns per thread (Mc=1280 worst case)

// ---- workspace layout ----
#define EW_ELEMS  ((size_t)N_NODES * N_MID)        // 2,293,760
#define EW_BYTES  (EW_ELEMS * 4)                   // 9,175,040 (16B aligned)
#define HDR_OFF   EW_BYTES
#define CMAP_OFF  (HDR_OFF + 16)
#define OCOL_OFF  (CMAP_OFF + N_MID * 4)
#define BIASC_OFF (OCOL_OFF + N_MID * 4)
#define WS_NEED   (BIASC_OFF + N_MID * 4)

// ============================================================
// Setup kernel A: compact existing columns (1 wave).
// cmap[cc] = original mid index of compacted col cc; ocol[cc] = output col or -1;
// biasc[cc] = bias. hdr = {Mc, Kc, KQ, Mpad}; Mpad = Mc rounded to 256 (Kc mult of 4).
// ============================================================
__global__ void build_maps_kernel(const int* __restrict__ exist,
                                  const float* __restrict__ bias,
                                  int* __restrict__ hdr,
                                  int* __restrict__ cmap,
                                  int* __restrict__ ocol,
                                  float* __restrict__ biasc) {
    const int lane = threadIdx.x;   // 64 threads
    int base = 0;
    for (int r = 0; r < N_MID / 64; ++r) {
        const int i = r * 64 + lane;
        const int e = exist[i];
        const unsigned long long m  = __ballot(e != 0);
        const unsigned long long lt = (lane == 0) ? 0ull : (~0ull >> (64 - lane));
        const int pos = base + __popcll(m & lt);
        if (e) {
            cmap[pos]  = i;
            ocol[pos]  = (i >= N_MID - OUT_DIM) ? (i - (N_MID - OUT_DIM)) : -1;
            biasc[pos] = bias[i];
        }
        base += __popcll(m);
    }
    // zero-fill pads (base is wave-uniform)
    for (int idx = base + lane; idx < N_MID; idx += 64) {
        cmap[idx] = 0; ocol[idx] = -1; biasc[idx] = 0.f;
    }
    if (lane == 0) {
        const int Mc   = base;
        const int Mpad = (Mc + 255) & ~255;   // Kc multiple of 4 -> float4-aligned c0
        const int Kc   = Mpad / 64;
        hdr[0] = Mc; hdr[1] = Kc; hdr[2] = Kc / 4; hdr[3] = Mpad;
    }
}

// ============================================================
// Setup kernel B: gather eff_w into compacted layout.
// ew[r][cc] (stride N_MID): r<512 -> input row r; r=512+cs -> source node cs
// (compacted). Pad columns / pad rows are zero.
// ============================================================
__global__ __launch_bounds__(NT)
void gather_kernel(const float* __restrict__ w, const int* __restrict__ conn,
                   const int* __restrict__ hdr, const int* __restrict__ cmap,
                   float* __restrict__ ew) {
    const int Mc = hdr[0];
    const size_t idx = (size_t)blockIdx.x * NT + threadIdx.x;
    const int r = (int)(idx / N_MID);
    const int c = (int)(idx % N_MID);
    float v = 0.f;
    if (c < Mc) {
        const int sc = cmap[c];
        int sr = -1;
        if (r < IN_DIM) sr = r;
        else { const int cs = r - IN_DIM; if (cs < Mc) sr = IN_DIM + cmap[cs]; }
        if (sr >= 0) {
            const size_t o = (size_t)sr * N_MID + sc;
            v = w[o] * (float)conn[o];
        }
    }
    ew[idx] = v;
}

// ============================================================
// Main kernel: compacted space. thread t: rg=t&3 -> rows {rg,rg+4,rg+8,rg+12},
// cg=t>>2 owns compacted cols [cg*Kc, cg*Kc+Kc). acc[4][KMAX] in regs.
// Phase 2 chunked: owner cg==bb resolves its Kc nodes serially (regs),
// writes res to LDS, ONE barrier, cg>bb do dense rank-Kc update.
// ============================================================
__global__ __launch_bounds__(NT, 4)
void net2_kernel(const float* __restrict__ x,
                 const float* __restrict__ ew,
                 const int* __restrict__ hdr,
                 const int* __restrict__ outcol,
                 const float* __restrict__ biasc,
                 float* __restrict__ out) {
    __shared__ __align__(16) float xs[ROWS * XPAD];          // 33,280 B
    __shared__ __align__(16) float res4[2][KMAX][ROWS];      //  2,560 B
    float* bias_s = xs;                 // overlay after phase 1
    int*   oc_s   = (int*)(xs + N_MID);

    const int t  = threadIdx.x;
    const int rg = t & 3;
    const int cg = t >> 2;
    const int r0 = blockIdx.x * ROWS;
    const int Mc = hdr[0], Kc = hdr[1], KQ = hdr[2];
    const int c0 = cg * Kc;             // multiple of 4 -> float4-aligned

    // ---- stage x tile ----
    {
        const float4* xg = (const float4*)(x + (size_t)r0 * IN_DIM);
        for (int idx = t; idx < ROWS * IN_DIM / 4; idx += NT) {
            const int r = idx >> 7, jj = idx & 127;
            *(float4*)&xs[r * XPAD + jj * 4] = xg[idx];
        }
    }
    __syncthreads();

    float acc[4][KMAX];
#pragma unroll
    for (int a = 0; a < 4; ++a)
#pragma unroll
        for (int k = 0; k < KMAX; ++k) acc[a][k] = 0.f;

    // ---- phase 1: input GEMM over compacted cols, j unrolled by 4 ----
    for (int j4 = 0; j4 < IN_DIM / 4; ++j4) {
        float xv[4][4];   // [u][a]
#pragma unroll
        for (int a = 0; a < 4; ++a) {
            const float4 v = *(const float4*)&xs[(rg + 4 * a) * XPAD + j4 * 4];
            xv[0][a] = v.x; xv[1][a] = v.y; xv[2][a] = v.z; xv[3][a] = v.w;
        }
        const float* wp = ew + (size_t)(j4 * 4) * N_MID + c0;
#pragma unroll
        for (int u = 0; u < 4; ++u) {
#pragma unroll
            for (int q = 0; q < 5; ++q) if (q < KQ) {
                const float4 w4 = *(const float4*)&wp[(size_t)u * N_MID + q * 4];
                const float wq[4] = {w4.x, w4.y, w4.z, w4.w};
#pragma unroll
                for (int uu = 0; uu < 4; ++uu) {
                    const int k = q * 4 + uu;
#pragma unroll
                    for (int a = 0; a < 4; ++a)
                        acc[a][k] = fmaf(xv[u][a], wq[uu], acc[a][k]);
                }
            }
        }
    }
    __syncthreads();

    // ---- overlay compacted bias / out-col into LDS ----
    for (int idx = t; idx < N_MID; idx += NT) {
        bias_s[idx] = biasc[idx];
        oc_s[idx]   = outcol[idx];
    }
    __syncthreads();

    // ---- phase 2: chunked sequential resolve ----
    int p = 0;
    for (int bb = 0; bb < 64; ++bb) {
        const int cbase = bb * Kc;
        if (cbase >= Mc) break;                    // uniform

        if (cg == bb) {
            // owner: serial resolve of this chunk (4 lanes, 4 rows each)
            const float* wtr = ew + (size_t)(IN_DIM + cbase) * N_MID + c0;
#pragma unroll
            for (int kk = 0; kk < KMAX; ++kk) {
                if (kk < Kc && cbase + kk < Mc) {
                    const int cc = cbase + kk;
                    float res[4];
#pragma unroll
                    for (int a = 0; a < 4; ++a) {
                        const float v = acc[a][kk];
                        const float s = __fdividef(1.f, 1.f + __expf(-v));
                        res[a] = s + bias_s[cc];   // exist==1 in compacted space
                    }
                    *(float4*)&res4[p][kk][rg * 4] =
                        make_float4(res[0], res[1], res[2], res[3]);
                    const int oc = oc_s[cc];
                    if (oc >= 0) {
#pragma unroll
                        for (int a = 0; a < 4; ++a)
                            out[(size_t)(r0 + rg + 4 * a) * OUT_DIM + oc] = res[a];
                    }
                    // in-chunk triangle: update k2 > kk
                    const float* wr = wtr + (size_t)kk * N_MID;
#pragma unroll
                    for (int q = 0; q < 5; ++q) if (q < KQ && q * 4 + 3 > kk) {
                        const float4 w4 = *(const float4*)&wr[q * 4];
                        const float wq[4] = {w4.x, w4.y, w4.z, w4.w};
#pragma unroll
                        for (int uu = 0; uu < 4; ++uu) {
                            const int k2 = q * 4 + uu;
                            if (k2 > kk) {
#pragma unroll
                                for (int a = 0; a < 4; ++a)
                                    acc[a][k2] = fmaf(res[a], wq[uu], acc[a][k2]);
                            }
                        }
                    }
                }
            }
        }
        __syncthreads();                            // the ONLY barrier per chunk

        if (cg > bb) {
            // dense rank-Kc update from this chunk's res
            const float* wb = ew + (size_t)(IN_DIM + cbase) * N_MID + c0;
            for (int kk = 0; kk < Kc; ++kk) {
                if (cbase + kk >= Mc) break;        // uniform
                const float4 rv = *(const float4*)&res4[p][kk][rg * 4];
                const float rs[4] = {rv.x, rv.y, rv.z, rv.w};
                const float* wr = wb + (size_t)kk * N_MID;
#pragma unroll
                for (int q = 0; q < 5; ++q) if (q < KQ) {
                    const float4 w4 = *(const float4*)&wr[q * 4];
                    const float wq[4] = {w4.x, w4.y, w4.z, w4.w};
#pragma unroll
                    for (int uu = 0; uu < 4; ++uu) {
                        const int k = q * 4 + uu;
#pragma unroll
                        for (int a = 0; a < 4; ++a)
                            acc[a][k] = fmaf(rs[a], wq[uu], acc[a][k]);
                    }
                }
            }
        }
        p ^= 1;
    }
}

// ============================================================
// Fallback (ws too small): round-1 monolithic kernel, conn folded inline.
// ============================================================
__global__ __launch_bounds__(NT, 4)
void net_v1_kernel(const float* __restrict__ x,
                   const float* __restrict__ wsrc,
                   const int* __restrict__ conn,
                   const float* __restrict__ bias,
                   const int* __restrict__ exist,
                   float* __restrict__ out) {
    __shared__ float xs[ROWS * XPAD];
    __shared__ float res_s[2][ROWS];
    float* bias_s  = xs;
    float* exist_s = xs + N_MID;

    const int t = threadIdx.x, rg = t & 3, cg = t >> 2;
    const int r0 = blockIdx.x * ROWS;
    const int c0 = cg * 20;

    {
        const float4* xg = (const float4*)(x + (size_t)r0 * IN_DIM);
        for (int idx = t; idx < ROWS * IN_DIM / 4; idx += NT) {
            const int r = idx >> 7, jj = idx & 127;
            *(float4*)&xs[r * XPAD + jj * 4] = xg[idx];
        }
    }
    __syncthreads();

    float acc[4][20];
#pragma unroll
    for (int a = 0; a < 4; ++a)
#pragma unroll
        for (int k = 0; k < 20; ++k) acc[a][k] = 0.f;

    for (int j = 0; j < IN_DIM; ++j) {
        const size_t woff = (size_t)j * N_MID + c0;
        const float xv0 = xs[rg * XPAD + j];
        const float xv1 = xs[(rg + 4) * XPAD + j];
        const float xv2 = xs[(rg + 8) * XPAD + j];
        const float xv3 = xs[(rg + 12) * XPAD + j];
#pragma unroll
        for (int q = 0; q < 5; ++q) {
            float4 w4 = *(const float4*)(wsrc + woff + q * 4);
            const int4 c4 = *(const int4*)(conn + woff + q * 4);
            w4.x *= (float)c4.x; w4.y *= (float)c4.y;
            w4.z *= (float)c4.z; w4.w *= (float)c4.w;
            const float wq[4] = {w4.x, w4.y, w4.z, w4.w};
#pragma unroll
            for (int u = 0; u < 4; ++u) {
                const int k = q * 4 + u;
                acc[0][k] = fmaf(xv0, wq[u], acc[0][k]);
                acc[1][k] = fmaf(xv1, wq[u], acc[1][k]);
                acc[2][k] = fmaf(xv2, wq[u], acc[2][k]);
                acc[3][k] = fmaf(xv3, wq[u], acc[3][k]);
            }
        }
    }
    __syncthreads();
    for (int idx = t; idx < N_MID; idx += NT) {
        bias_s[idx]  = bias[idx];
        exist_s[idx] = (float)exist[idx];
    }
    __syncthreads();

    int p = 0;
    for (int bb = 0; bb < 64; ++bb) {
#pragma unroll
        for (int kk = 0; kk < 20; ++kk) {
            const int i = bb * 20 + kk;
            const float e = exist_s[i];
            if (e != 0.f) {
                if (cg == bb) {
                    const float bv = bias_s[i];
#pragma unroll
                    for (int a = 0; a < 4; ++a) {
                        const float v = acc[a][kk];
                        const float s = __fdividef(1.f, 1.f + __expf(-v));
                        const float res = (s + bv) * e;
                        res_s[p][rg + 4 * a] = res;
                        if (i >= N_MID - OUT_DIM)
                            out[(size_t)(r0 + rg + 4 * a) * OUT_DIM + (i - (N_MID - OUT_DIM))] = res;
                    }
                }
                __syncthreads();
                const float rv0 = res_s[p][rg];
                const float rv1 = res_s[p][rg + 4];
                const float rv2 = res_s[p][rg + 8];
                const float rv3 = res_s[p][rg + 12];
                const size_t woff = (size_t)(IN_DIM + i) * N_MID + c0;
                if (cg > bb) {
#pragma unroll
                    for (int q = 0; q < 5; ++q) {
                        float4 w4 = *(const float4*)(wsrc + woff + q * 4);
                        const int4 c4 = *(const int4*)(conn + woff + q * 4);
                        w4.x *= (float)c4.x; w4.y *= (float)c4.y;
                        w4.z *= (float)c4.z; w4.w *= (float)c4.w;
                        const float wq[4] = {w4.x, w4.y, w4.z, w4.w};
#pragma unroll
                        for (int u = 0; u < 4; ++u) {
                            const int k = q * 4 + u;
                            acc[0][k] = fmaf(rv0, wq[u], acc[0][k]);
                            acc[1][k] = fmaf(rv1, wq[u], acc[1][k]);
                            acc[2][k] = fmaf(rv2, wq[u], acc[2][k]);
                            acc[3][k] = fmaf(rv3, wq[u], acc[3][k]);
                        }
                    }
                } else if (cg == bb) {
#pragma unroll
                    for (int k = kk + 1; k < 20; ++k) {
                        float w = wsrc[woff + k] * (float)conn[woff + k];
                        acc[0][k] = fmaf(rv0, w, acc[0][k]);
                        acc[1][k] = fmaf(rv1, w, acc[1][k]);
                        acc[2][k] = fmaf(rv2, w, acc[2][k]);
                        acc[3][k] = fmaf(rv3, w, acc[3][k]);
                    }
                }
                p ^= 1;
            }
        }
    }
}

extern "C" void kernel_launch(void* const* d_in, const int* in_sizes, int n_in,
                              void* d_out, int out_size, void* d_ws, size_t ws_size,
                              hipStream_t stream) {
    const float* x      = (const float*)d_in[0];
    const float* weight = (const float*)d_in[1];
    const float* bias   = (const float*)d_in[2];
    const int*   conn   = (const int*)d_in[3];
    const int*   exist  = (const int*)d_in[4];
    float*       out    = (float*)d_out;

    if (ws_size >= WS_NEED) {
        char* ws = (char*)d_ws;
        float* ew    = (float*)ws;
        int*   hdr   = (int*)(ws + HDR_OFF);
        int*   cmap  = (int*)(ws + CMAP_OFF);
        int*   ocol  = (int*)(ws + OCOL_OFF);
        float* biasc = (float*)(ws + BIASC_OFF);
        build_maps_kernel<<<1, 64, 0, stream>>>(exist, bias, hdr, cmap, ocol, biasc);
        gather_kernel<<<(int)(EW_ELEMS / NT), NT, 0, stream>>>(weight, conn, hdr, cmap, ew);
        net2_kernel<<<BATCH / ROWS, NT, 0, stream>>>(x, ew, hdr, ocol, biasc, out);
    } else {
        net_v1_kernel<<<BATCH / ROWS, NT, 0, stream>>>(x, weight, conn, bias, exist, out);
    }
}